// Round 1
// baseline (558.351 us; speedup 1.0000x reference)
//
#include <hip/hip_runtime.h>
#include <cstdint>
#include <cstddef>

#define NEGV (-1e30f)

constexpr int C_ = 512, H_ = 128, W_ = 128;
constexpr int P_ = 16384;   // H*W

typedef short bf16x8 __attribute__((ext_vector_type(8)));
typedef float f32x4  __attribute__((ext_vector_type(4)));
#define MFMA16(a, b, c) __builtin_amdgcn_mfma_f32_16x16x32_bf16((a), (b), (c), 0, 0, 0)

// 16B-slot XOR swizzle for a [128][128]-ushort LDS tile (row stride 256B).
// cu = ushort column index; slot (16B) XOR'd with row&15 -> stride-256B
// ds_read_b128 column reads are conflict-free.
#define SWZI(r, cu) ((((r) << 7)) + (((((cu) >> 3) ^ ((r) & 15))) << 3) + ((cu) & 7))

__device__ inline unsigned short f2bf(float f) {
    union { float f; uint32_t i; } t; t.f = f;
    uint32_t r = t.i + 0x7FFFu + ((t.i >> 16) & 1u);   // RNE
    return (unsigned short)(r >> 16);
}
__device__ inline float bf2f(unsigned short u) {
    union { uint32_t i; float f; } t; t.i = (uint32_t)u << 16; return t.f;
}
// add two packed-bf16 pairs in fp32, repack (RNE)
__device__ inline uint32_t bfadd2(uint32_t a, uint32_t b) {
    union { uint32_t i; float f; } alo, ahi, blo, bhi;
    alo.i = a << 16; ahi.i = a & 0xffff0000u;
    blo.i = b << 16; bhi.i = b & 0xffff0000u;
    const float lo = alo.f + blo.f, hi = ahi.f + bhi.f;
    return (uint32_t)f2bf(lo) | ((uint32_t)f2bf(hi) << 16);
}
__device__ inline uint4 bfadd8(const uint4 a, const uint4 b) {
    uint4 r; r.x = bfadd2(a.x, b.x); r.y = bfadd2(a.y, b.y);
    r.z = bfadd2(a.z, b.z); r.w = bfadd2(a.w, b.w); return r;
}

// ---------------------------------------------------------------------------
// Weight conversion: Wq,Wk -> Wqkbf[128][512] (q rows 0..63, k rows 64..127);
// Wv -> Wvbf[512][512]. 4 elems/thread.
__global__ __launch_bounds__(256) void kwconv(
    const float* __restrict__ Wq, const float* __restrict__ Wk,
    const float* __restrict__ Wv,
    unsigned short* __restrict__ Wqkbf, unsigned short* __restrict__ Wvbf)
{
    const int i4 = (blockIdx.x * 256 + threadIdx.x) * 4;
    const float* src; unsigned short* dst; int off;
    if (i4 < 32768)       { src = Wq + i4;          dst = Wqkbf + i4; }
    else if (i4 < 65536)  { off = i4 - 32768; src = Wk + off; dst = Wqkbf + i4; }
    else                  { off = i4 - 65536; src = Wv + off; dst = Wvbf + off; }
    const float4 v = *(const float4*)src;
    ushort4 u; u.x = f2bf(v.x); u.y = f2bf(v.y); u.z = f2bf(v.z); u.w = f2bf(v.w);
    *(ushort4*)dst = u;
}

// ---------------------------------------------------------------------------
// x[b][c][h][w] fp32 -> xTbf[b][c][w][h] bf16 (per-map 128x128 transpose)
__global__ __launch_bounds__(256) void kprep1(
    const float* __restrict__ x, unsigned short* __restrict__ xTbf)
{
    __shared__ float t[32][33];
    const int tx = threadIdx.x, ty = threadIdx.y;
    const int h0 = (blockIdx.x >> 2) * 32, w0 = (blockIdx.x & 3) * 32;
    const size_t base = (size_t)blockIdx.y * P_;
#pragma unroll
    for (int k = 0; k < 4; k++)
        t[ty + 8 * k][tx] = x[base + (size_t)(h0 + ty + 8 * k) * 128 + w0 + tx];
    __syncthreads();
#pragma unroll
    for (int k = 0; k < 4; k++)
        xTbf[base + (size_t)(w0 + ty + 8 * k) * 128 + h0 + tx] = f2bf(t[tx][ty + 8 * k]);
}

// x[b][c][p] fp32 -> xbfT[b][p][c] bf16  (c <-> p transpose), tiles 32c x 32p
__global__ __launch_bounds__(256) void kprep2(
    const float* __restrict__ x, unsigned short* __restrict__ xbfT)
{
    __shared__ float t[32][33];
    const int tx = threadIdx.x, ty = threadIdx.y;
    const int p0 = blockIdx.x * 32, c0 = blockIdx.y * 32, b = blockIdx.z;
#pragma unroll
    for (int k = 0; k < 4; k++)
        t[ty + 8 * k][tx] = x[((size_t)(b * C_ + c0 + ty + 8 * k)) * P_ + p0 + tx];
    __syncthreads();
#pragma unroll
    for (int k = 0; k < 4; k++)
        xbfT[((size_t)b * P_ + p0 + ty + 8 * k) * C_ + c0 + tx] = f2bf(t[tx][ty + 8 * k]);
}

// ---------------------------------------------------------------------------
// MFMA GEMM, K=512. D[m][n=p] = sum_c A[m][c] * Bm[p][c].
// A row-major [M][512] bf16; Bm [b][p][512] bf16 (p-major).
// If Bm2 != null, B operand = fp32(Bm) + fp32(Bm2), combined in staging.
// mode qk (outbf): store bf16 at qkP[b][p][mk]  (mk = row index m)
// mode final (outf): out[b][m][p] = gamma*acc + addx[same], fp32
__global__ __launch_bounds__(256) void kgemm_mfma(
    const unsigned short* __restrict__ A, const unsigned short* __restrict__ Bm,
    const unsigned short* __restrict__ Bm2,
    unsigned short* __restrict__ outbf, float* __restrict__ outf,
    const float* __restrict__ addx, const float* __restrict__ gammap)
{
    __shared__ __attribute__((aligned(16))) unsigned short sA[128 * 72];
    __shared__ __attribute__((aligned(16))) unsigned short sB[128 * 72];
    const int tid = threadIdx.x;
    const int pbase = blockIdx.x * 128, mt = blockIdx.y, b = blockIdx.z;
    const int lane = tid & 63, wv = tid >> 6;
    const int m0 = (wv >> 1) * 64, p0 = (wv & 1) * 64;
    const int fr = lane & 15, fq = lane >> 4;

    f32x4 acc[4][4];
#pragma unroll
    for (int i = 0; i < 4; i++)
#pragma unroll
        for (int j = 0; j < 4; j++) acc[i][j] = (f32x4){0.f, 0.f, 0.f, 0.f};

    const size_t arow0 = (size_t)(mt * 128) * 512;
    const size_t brow0 = ((size_t)b * P_ + pbase) * 512;

    for (int kc = 0; kc < 512; kc += 64) {
#pragma unroll
        for (int rep = 0; rep < 4; rep++) {
            const int idx = rep * 256 + tid;
            const int kg = idx & 7, r = idx >> 3;
            *(uint4*)&sA[r * 72 + kg * 8] = *(const uint4*)&A[arow0 + (size_t)r * 512 + kc + kg * 8];
            const size_t boff = brow0 + (size_t)r * 512 + kc + kg * 8;
            uint4 vb = *(const uint4*)&Bm[boff];
            if (Bm2) vb = bfadd8(vb, *(const uint4*)&Bm2[boff]);
            *(uint4*)&sB[r * 72 + kg * 8] = vb;
        }
        __syncthreads();
#pragma unroll
        for (int kk = 0; kk < 64; kk += 32) {
            bf16x8 af[4], bfv[4];
#pragma unroll
            for (int t = 0; t < 4; t++) af[t]  = *(const bf16x8*)&sA[(m0 + t * 16 + fr) * 72 + kk + fq * 8];
#pragma unroll
            for (int t = 0; t < 4; t++) bfv[t] = *(const bf16x8*)&sB[(p0 + t * 16 + fr) * 72 + kk + fq * 8];
#pragma unroll
            for (int i = 0; i < 4; i++)
#pragma unroll
                for (int j = 0; j < 4; j++)
                    acc[i][j] = MFMA16(af[i], bfv[j], acc[i][j]);
        }
        __syncthreads();
    }

    if (outbf) {
        // qkP[b][p][mk] bf16, pack 4 consecutive mk (quad*4+r) per store
#pragma unroll
        for (int tj = 0; tj < 4; tj++) {
            const int p_g = pbase + p0 + tj * 16 + fr;
            const size_t rowo = ((size_t)b * P_ + p_g) * 128;
#pragma unroll
            for (int ti = 0; ti < 4; ti++) {
                const int mk = m0 + ti * 16 + fq * 4;
                ushort4 u;
                u.x = f2bf(acc[ti][tj][0]); u.y = f2bf(acc[ti][tj][1]);
                u.z = f2bf(acc[ti][tj][2]); u.w = f2bf(acc[ti][tj][3]);
                *(ushort4*)&outbf[rowo + mk] = u;
            }
        }
    } else {
        const float g = gammap[0];
#pragma unroll
        for (int ti = 0; ti < 4; ti++)
#pragma unroll
            for (int r = 0; r < 4; r++) {
                const int m_g = mt * 128 + m0 + ti * 16 + fq * 4 + r;
                const size_t rowo = ((size_t)(b * 512 + m_g)) * P_;
#pragma unroll
                for (int tj = 0; tj < 4; tj++) {
                    const int p_g = pbase + p0 + tj * 16 + fr;
                    outf[rowo + p_g] = fmaf(g, acc[ti][tj][r], addx[rowo + p_g]);
                }
            }
    }
}

// ---------------------------------------------------------------------------
// Logits, fused row/col via blockIdx.z:
// per (b, s): E[i][j] = sum_{m<64} Q[m][i]*K[m][j], Q/K from qkP[b][p][mk]
// mode 0 (row, -> ERow): p(i) = s*128 + i
// mode 1 (col, -> ECol): p(i) = i*128 + s, diag mask
__global__ __launch_bounds__(256) void klogits(
    const unsigned short* __restrict__ qkP,
    float* __restrict__ ERow, float* __restrict__ ECol)
{
    __shared__ __attribute__((aligned(16))) unsigned short sPM[128 * 136];
    const int tid = threadIdx.x;
    const int s = blockIdx.x, b = blockIdx.y, mode = blockIdx.z;
    const int rowMul  = mode ? 1 : 128;
    const int rowStep = mode ? 128 : 1;
    float* E = mode ? ECol : ERow;
    const size_t qbase = (size_t)b * P_ * 128;
    const int rb = s * rowMul;
#pragma unroll
    for (int rep = 0; rep < 8; rep++) {
        const int idx = rep * 256 + tid;
        const int mkg = idx & 15, i = idx >> 4;
        *(uint4*)&sPM[i * 136 + mkg * 8] =
            *(const uint4*)&qkP[qbase + (size_t)(rb + i * rowStep) * 128 + mkg * 8];
    }
    __syncthreads();

    const int lane = tid & 63, wv = tid >> 6;
    const int i0 = (wv >> 1) * 64, j0 = (wv & 1) * 64;
    const int fr = lane & 15, fq = lane >> 4;

    f32x4 acc[4][4];
#pragma unroll
    for (int i = 0; i < 4; i++)
#pragma unroll
        for (int j = 0; j < 4; j++) acc[i][j] = (f32x4){0.f, 0.f, 0.f, 0.f};

#pragma unroll
    for (int kk = 0; kk < 64; kk += 32) {
        bf16x8 af[4], bfv[4];
#pragma unroll
        for (int t = 0; t < 4; t++) af[t]  = *(const bf16x8*)&sPM[(i0 + t * 16 + fr) * 136 + kk + fq * 8];
#pragma unroll
        for (int t = 0; t < 4; t++) bfv[t] = *(const bf16x8*)&sPM[(j0 + t * 16 + fr) * 136 + 64 + kk + fq * 8];
#pragma unroll
        for (int i = 0; i < 4; i++)
#pragma unroll
            for (int j = 0; j < 4; j++)
                acc[i][j] = MFMA16(af[i], bfv[j], acc[i][j]);
    }

    float* Eb = E + ((size_t)(b * 128 + s)) * P_;
#pragma unroll
    for (int ti = 0; ti < 4; ti++)
#pragma unroll
        for (int r = 0; r < 4; r++) {
            const int i_g = i0 + ti * 16 + fq * 4 + r;
#pragma unroll
            for (int tj = 0; tj < 4; tj++) {
                const int j_g = j0 + tj * 16 + fr;
                float v = acc[ti][tj][r];
                if (mode && i_g == j_g) v = NEGV;
                Eb[(size_t)i_g * 128 + j_g] = v;
            }
        }
}

// ---------------------------------------------------------------------------
// Joint softmax over 128 row + 128 col logits per pixel; fp32 in, bf16 out.
__global__ __launch_bounds__(256) void ksoftmax(
    const float* __restrict__ ER, const float* __restrict__ EC,
    unsigned short* __restrict__ AR, unsigned short* __restrict__ AC)
{
    const int lane = threadIdx.x & 63;
    const int pix = blockIdx.x * 4 + (threadIdx.x >> 6);
    const int b = pix >> 14, rem = pix & 16383;
    const int h = rem >> 7, w = rem & 127;
    const size_t ro = ((size_t)((b * 128 + h) * 128 + w)) * 128;
    const size_t co = ((size_t)((b * 128 + w) * 128 + h)) * 128;
    const float2 r = *(const float2*)(ER + ro + lane * 2);
    const float2 c = *(const float2*)(EC + co + lane * 2);
    float mx = fmaxf(fmaxf(r.x, r.y), fmaxf(c.x, c.y));
#pragma unroll
    for (int off = 32; off > 0; off >>= 1) mx = fmaxf(mx, __shfl_xor(mx, off));
    const float e0 = __expf(r.x - mx), e1 = __expf(r.y - mx);
    const float e2 = __expf(c.x - mx), e3 = __expf(c.y - mx);
    float sm = e0 + e1 + e2 + e3;
#pragma unroll
    for (int off = 32; off > 0; off >>= 1) sm += __shfl_xor(sm, off);
    const float inv = 1.0f / sm;
    ushort2 u0; u0.x = f2bf(e0 * inv); u0.y = f2bf(e1 * inv);
    ushort2 u1; u1.x = f2bf(e2 * inv); u1.y = f2bf(e3 * inv);
    *(ushort2*)(AR + ro + lane * 2) = u0;
    *(ushort2*)(AC + co + lane * 2) = u1;
}

// ---------------------------------------------------------------------------
// Fused aggregation. Grid (s=128, b=4, mode=2), 256 threads.
// mode 0 (row): ySumR[b][p=s*128+i][c] = sum_j ARow[b][s][i][j] * x[b][c][s*128+j]
// mode 1 (col): ySumC[b][p=i*128+s][c] = sum_j ACol[b][s][i][j] * xTbf[b][c][s*128+j]
// Attention tile staged once; C looped in 4 tiles of 128 inside the block.
// MFMA computes D[m=c][n=i] so each lane holds 4 consecutive c -> ushort4 stores.
__global__ __launch_bounds__(256) void kagg2(
    const unsigned short* __restrict__ ARow, const unsigned short* __restrict__ ACol,
    const float* __restrict__ x, const unsigned short* __restrict__ xTbf,
    unsigned short* __restrict__ ySumR, unsigned short* __restrict__ ySumC)
{
    __shared__ __attribute__((aligned(16))) unsigned short sAttn[128 * 128];
    __shared__ __attribute__((aligned(16))) unsigned short sX[128 * 128];
    const int tid = threadIdx.x;
    const int s = blockIdx.x, b = blockIdx.y, mode = blockIdx.z;
    const int lane = tid & 63, wv = tid >> 6;
    const int m0 = (wv >> 1) * 64, n0 = (wv & 1) * 64;   // m = c tile, n = i tile
    const int fr = lane & 15, fq = lane >> 4;

    // stage attention tile 128x128 once (swizzled)
    const unsigned short* At = (mode ? ACol : ARow) + ((size_t)(b * 128 + s)) * P_;
#pragma unroll
    for (int rep = 0; rep < 8; rep++) {
        const int idx = rep * 256 + tid;
        const int jg = idx & 15, row = idx >> 4;
        *(uint4*)&sAttn[SWZI(row, jg * 8)] = *(const uint4*)&At[(size_t)row * 128 + jg * 8];
    }

    unsigned short* yS = mode ? ySumC : ySumR;

    for (int ct = 0; ct < 4; ct++) {
        // stage X[cc][j]: row mode from fp32 x (convert), col mode from xTbf
        if (mode == 0) {
#pragma unroll
            for (int rep = 0; rep < 16; rep++) {
                const int idx = rep * 256 + tid;
                const int jq = idx & 31, cc = idx >> 5;
                const float4 v = *(const float4*)&x[((size_t)(b * C_ + ct * 128 + cc)) * P_ + s * 128 + jq * 4];
                ushort4 u; u.x = f2bf(v.x); u.y = f2bf(v.y); u.z = f2bf(v.z); u.w = f2bf(v.w);
                *(ushort4*)&sX[SWZI(cc, jq * 4)] = u;
            }
        } else {
#pragma unroll
            for (int rep = 0; rep < 8; rep++) {
                const int idx = rep * 256 + tid;
                const int jg = idx & 15, cc = idx >> 4;
                *(uint4*)&sX[SWZI(cc, jg * 8)] =
                    *(const uint4*)&xTbf[((size_t)(b * C_ + ct * 128 + cc)) * P_ + s * 128 + jg * 8];
            }
        }
        __syncthreads();

        f32x4 acc[4][4];
#pragma unroll
        for (int i = 0; i < 4; i++)
#pragma unroll
            for (int j = 0; j < 4; j++) acc[i][j] = (f32x4){0.f, 0.f, 0.f, 0.f};

#pragma unroll
        for (int kk = 0; kk < 128; kk += 32) {
            bf16x8 af[4], bfv[4];
#pragma unroll
            for (int t = 0; t < 4; t++) af[t]  = *(const bf16x8*)&sX[SWZI(m0 + t * 16 + fr, kk + fq * 8)];
#pragma unroll
            for (int t = 0; t < 4; t++) bfv[t] = *(const bf16x8*)&sAttn[SWZI(n0 + t * 16 + fr, kk + fq * 8)];
#pragma unroll
            for (int i = 0; i < 4; i++)
#pragma unroll
                for (int j = 0; j < 4; j++)
                    acc[i][j] = MFMA16(af[i], bfv[j], acc[i][j]);
        }

        // epilogue: lane holds c = cg0 + ti*16 + {0..3}, i = n0 + tj*16 + fr
        const int cg0 = ct * 128 + m0 + fq * 4;
#pragma unroll
        for (int tj = 0; tj < 4; tj++) {
            const int i_g = n0 + tj * 16 + fr;
            const size_t p = mode ? ((size_t)i_g * 128 + s) : ((size_t)s * 128 + i_g);
            unsigned short* rowp = yS + ((size_t)b * P_ + p) * 512;
#pragma unroll
            for (int ti = 0; ti < 4; ti++) {
                ushort4 u;
                u.x = f2bf(acc[ti][tj][0]); u.y = f2bf(acc[ti][tj][1]);
                u.z = f2bf(acc[ti][tj][2]); u.w = f2bf(acc[ti][tj][3]);
                *(ushort4*)&rowp[cg0 + ti * 16] = u;
            }
        }
        __syncthreads();   // all waves done reading sX before next ct overwrites it
    }
}

// ---------------------------------------------------------------------------
extern "C" void kernel_launch(void* const* d_in, const int* in_sizes, int n_in,
                              void* d_out, int out_size, void* d_ws, size_t ws_size,
                              hipStream_t stream) {
    const float* x     = (const float*)d_in[0];
    const float* Wq    = (const float*)d_in[1];
    const float* Wk    = (const float*)d_in[2];
    const float* Wv    = (const float*)d_in[3];
    const float* gamma = (const float*)d_in[4];
    float* out = (float*)d_out;

    char* base = (char*)d_ws;
    unsigned short* Wqkbf = (unsigned short*)base;             base += 131072;      // 128x512
    unsigned short* Wvbf  = (unsigned short*)base;             base += 524288;      // 512x512
    unsigned short* xTbf  = (unsigned short*)base;             base += 67108864;    // [b][c][w][h]
    unsigned short* xbfT  = (unsigned short*)base;             base += 67108864;    // [b][p][c]
    unsigned short* qkP   = (unsigned short*)base;             base += 16777216;    // [b][p][mk]
    float*          ERow  = (float*)base;                      base += 33554432;    // [b][h][i][j]
    float*          ECol  = (float*)base;                      base += 33554432;    // [b][w][i][j]
    unsigned short* ARow  = (unsigned short*)base;             base += 16777216;
    unsigned short* ACol  = (unsigned short*)base;             base += 16777216;
    unsigned short* ySumR = (unsigned short*)base;             base += 67108864;    // [b][p][c]
    // ySumC aliases the dead ERow+ECol region (exactly 64 MiB, free after ksoftmax)
    unsigned short* ySumC = (unsigned short*)ERow;

    kwconv<<<320, 256, 0, stream>>>(Wq, Wk, Wv, Wqkbf, Wvbf);
    kprep1<<<dim3(16, 2048), dim3(32, 8), 0, stream>>>(x, xTbf);
    kprep2<<<dim3(512, 16, 4), dim3(32, 8), 0, stream>>>(x, xbfT);
    // qk[b][p][mk] = Wqk @ x
    kgemm_mfma<<<dim3(128, 1, 4), 256, 0, stream>>>(Wqkbf, xbfT, nullptr, qkP, nullptr, nullptr, nullptr);
    // row (eW) + col (eH, diag-masked) logits in one launch
    klogits<<<dim3(128, 4, 2), 256, 0, stream>>>(qkP, ERow, ECol);
    ksoftmax<<<16384, 256, 0, stream>>>(ERow, ECol, ARow, ACol);
    // fused row+col aggregation -> ySumR / ySumC (no RMW)
    kagg2<<<dim3(128, 4, 2), 256, 0, stream>>>(ARow, ACol, x, xTbf, ySumR, ySumC);
    // out = gamma * (Wv @ (ySumR + ySumC)) + x, sum fused into B staging
    kgemm_mfma<<<dim3(128, 4, 4), 256, 0, stream>>>(Wvbf, ySumR, ySumC, nullptr, out, x, gamma);
}

// Round 2
// 537.551 us; speedup vs baseline: 1.0387x; 1.0387x over previous
//
#include <hip/hip_runtime.h>
#include <cstdint>
#include <cstddef>

#define NEGV (-1e30f)

constexpr int C_ = 512, H_ = 128, W_ = 128;
constexpr int P_ = 16384;   // H*W

typedef short bf16x8 __attribute__((ext_vector_type(8)));
typedef float f32x4  __attribute__((ext_vector_type(4)));
#define MFMA16(a, b, c) __builtin_amdgcn_mfma_f32_16x16x32_bf16((a), (b), (c), 0, 0, 0)

// Swizzled LDS offsets (units: shorts). 16B slots XOR'd with row&7 so that
// stride-128B/256B column reads (ds_read_b128) spread across all banks.
// Rule #21: with global_load_lds the LDS dest is LINEAR (idx*16B) and the
// GLOBAL source slot is pre-XOR'd with the same involution; reads use SWZ*.
#define SWZ128(r, cs) (((r) << 7) + (((((cs) >> 3) ^ ((r) & 7))) << 3) + ((cs) & 7))
#define SWZ64(r, cs)  (((r) << 6) + (((((cs) >> 3) ^ ((r) & 7))) << 3) + ((cs) & 7))

__device__ inline void gl_lds16(const void* g, void* l) {
    __builtin_amdgcn_global_load_lds(
        (const __attribute__((address_space(1))) unsigned int*)g,
        (__attribute__((address_space(3))) unsigned int*)l, 16, 0, 0);
}

__device__ inline unsigned short f2bf(float f) {
    union { float f; uint32_t i; } t; t.f = f;
    uint32_t r = t.i + 0x7FFFu + ((t.i >> 16) & 1u);   // RNE
    return (unsigned short)(r >> 16);
}

// ---------------------------------------------------------------------------
// Weight conversion: Wq,Wk -> Wqkbf[128][512] (q rows 0..63, k rows 64..127);
// Wv -> Wvbf[512][512]. 4 elems/thread.
__global__ __launch_bounds__(256) void kwconv(
    const float* __restrict__ Wq, const float* __restrict__ Wk,
    const float* __restrict__ Wv,
    unsigned short* __restrict__ Wqkbf, unsigned short* __restrict__ Wvbf)
{
    const int i4 = (blockIdx.x * 256 + threadIdx.x) * 4;
    const float* src; unsigned short* dst; int off;
    if (i4 < 32768)       { src = Wq + i4;          dst = Wqkbf + i4; }
    else if (i4 < 65536)  { off = i4 - 32768; src = Wk + off; dst = Wqkbf + i4; }
    else                  { off = i4 - 65536; src = Wv + off; dst = Wvbf + off; }
    const float4 v = *(const float4*)src;
    ushort4 u; u.x = f2bf(v.x); u.y = f2bf(v.y); u.z = f2bf(v.z); u.w = f2bf(v.w);
    *(ushort4*)dst = u;
}

// ---------------------------------------------------------------------------
// x[b][c][h][w] fp32 -> xTbf[b][c][w][h] bf16 (per-map 128x128 transpose)
__global__ __launch_bounds__(256) void kprep1(
    const float* __restrict__ x, unsigned short* __restrict__ xTbf)
{
    __shared__ float t[32][33];
    const int tx = threadIdx.x, ty = threadIdx.y;
    const int h0 = (blockIdx.x >> 2) * 32, w0 = (blockIdx.x & 3) * 32;
    const size_t base = (size_t)blockIdx.y * P_;
#pragma unroll
    for (int k = 0; k < 4; k++)
        t[ty + 8 * k][tx] = x[base + (size_t)(h0 + ty + 8 * k) * 128 + w0 + tx];
    __syncthreads();
#pragma unroll
    for (int k = 0; k < 4; k++)
        xTbf[base + (size_t)(w0 + ty + 8 * k) * 128 + h0 + tx] = f2bf(t[tx][ty + 8 * k]);
}

// x[b][c][p] fp32 -> xbfT[b][p][c] bf16  (c <-> p transpose), tiles 32c x 32p
__global__ __launch_bounds__(256) void kprep2(
    const float* __restrict__ x, unsigned short* __restrict__ xbfT)
{
    __shared__ float t[32][33];
    const int tx = threadIdx.x, ty = threadIdx.y;
    const int p0 = blockIdx.x * 32, c0 = blockIdx.y * 32, b = blockIdx.z;
#pragma unroll
    for (int k = 0; k < 4; k++)
        t[ty + 8 * k][tx] = x[((size_t)(b * C_ + c0 + ty + 8 * k)) * P_ + p0 + tx];
    __syncthreads();
#pragma unroll
    for (int k = 0; k < 4; k++)
        xbfT[((size_t)b * P_ + p0 + ty + 8 * k) * C_ + c0 + tx] = f2bf(t[tx][ty + 8 * k]);
}

// ---------------------------------------------------------------------------
// QK projection GEMM, K=512. D[m][n=p] = sum_c A[m][c] * Bm[p][c].
// A = Wqkbf row-major [128][512]; Bm = xbfT [b][p][512] (p-major).
// Store bf16 at qkP[b][p][mk].
__global__ __launch_bounds__(256) void kgemmqk(
    const unsigned short* __restrict__ A, const unsigned short* __restrict__ Bm,
    unsigned short* __restrict__ outbf)
{
    __shared__ __attribute__((aligned(16))) unsigned short sA[128 * 72];
    __shared__ __attribute__((aligned(16))) unsigned short sB[128 * 72];
    const int tid = threadIdx.x;
    const int pbase = blockIdx.x * 128, b = blockIdx.z;
    const int lane = tid & 63, wv = tid >> 6;
    const int m0 = (wv >> 1) * 64, p0 = (wv & 1) * 64;
    const int fr = lane & 15, fq = lane >> 4;

    f32x4 acc[4][4];
#pragma unroll
    for (int i = 0; i < 4; i++)
#pragma unroll
        for (int j = 0; j < 4; j++) acc[i][j] = (f32x4){0.f, 0.f, 0.f, 0.f};

    const size_t brow0 = ((size_t)b * P_ + pbase) * 512;

    for (int kc = 0; kc < 512; kc += 64) {
#pragma unroll
        for (int rep = 0; rep < 4; rep++) {
            const int idx = rep * 256 + tid;
            const int kg = idx & 7, r = idx >> 3;
            *(uint4*)&sA[r * 72 + kg * 8] = *(const uint4*)&A[(size_t)r * 512 + kc + kg * 8];
            *(uint4*)&sB[r * 72 + kg * 8] = *(const uint4*)&Bm[brow0 + (size_t)r * 512 + kc + kg * 8];
        }
        __syncthreads();
#pragma unroll
        for (int kk = 0; kk < 64; kk += 32) {
            bf16x8 af[4], bfv[4];
#pragma unroll
            for (int t = 0; t < 4; t++) af[t]  = *(const bf16x8*)&sA[(m0 + t * 16 + fr) * 72 + kk + fq * 8];
#pragma unroll
            for (int t = 0; t < 4; t++) bfv[t] = *(const bf16x8*)&sB[(p0 + t * 16 + fr) * 72 + kk + fq * 8];
#pragma unroll
            for (int i = 0; i < 4; i++)
#pragma unroll
                for (int j = 0; j < 4; j++)
                    acc[i][j] = MFMA16(af[i], bfv[j], acc[i][j]);
        }
        __syncthreads();
    }

    // qkP[b][p][mk] bf16, pack 4 consecutive mk (quad*4+r) per store
#pragma unroll
    for (int tj = 0; tj < 4; tj++) {
        const int p_g = pbase + p0 + tj * 16 + fr;
        const size_t rowo = ((size_t)b * P_ + p_g) * 128;
#pragma unroll
        for (int ti = 0; ti < 4; ti++) {
            const int mk = m0 + ti * 16 + fq * 4;
            ushort4 u;
            u.x = f2bf(acc[ti][tj][0]); u.y = f2bf(acc[ti][tj][1]);
            u.z = f2bf(acc[ti][tj][2]); u.w = f2bf(acc[ti][tj][3]);
            *(ushort4*)&outbf[rowo + mk] = u;
        }
    }
}

// ---------------------------------------------------------------------------
// Logits, fused row/col via blockIdx.z:
// per (b, s): E[i][j] = sum_{m<64} Q[m][i]*K[m][j], Q/K from qkP[b][p][mk]
// mode 0 (row, -> ERow): p(i) = s*128 + i
// mode 1 (col, -> ECol): p(i) = i*128 + s, diag mask
__global__ __launch_bounds__(256) void klogits(
    const unsigned short* __restrict__ qkP,
    float* __restrict__ ERow, float* __restrict__ ECol)
{
    __shared__ __attribute__((aligned(16))) unsigned short sPM[128 * 136];
    const int tid = threadIdx.x;
    const int s = blockIdx.x, b = blockIdx.y, mode = blockIdx.z;
    const int rowMul  = mode ? 1 : 128;
    const int rowStep = mode ? 128 : 1;
    float* E = mode ? ECol : ERow;
    const size_t qbase = (size_t)b * P_ * 128;
    const int rb = s * rowMul;
#pragma unroll
    for (int rep = 0; rep < 8; rep++) {
        const int idx = rep * 256 + tid;
        const int mkg = idx & 15, i = idx >> 4;
        *(uint4*)&sPM[i * 136 + mkg * 8] =
            *(const uint4*)&qkP[qbase + (size_t)(rb + i * rowStep) * 128 + mkg * 8];
    }
    __syncthreads();

    const int lane = tid & 63, wv = tid >> 6;
    const int i0 = (wv >> 1) * 64, j0 = (wv & 1) * 64;
    const int fr = lane & 15, fq = lane >> 4;

    f32x4 acc[4][4];
#pragma unroll
    for (int i = 0; i < 4; i++)
#pragma unroll
        for (int j = 0; j < 4; j++) acc[i][j] = (f32x4){0.f, 0.f, 0.f, 0.f};

#pragma unroll
    for (int kk = 0; kk < 64; kk += 32) {
        bf16x8 af[4], bfv[4];
#pragma unroll
        for (int t = 0; t < 4; t++) af[t]  = *(const bf16x8*)&sPM[(i0 + t * 16 + fr) * 136 + kk + fq * 8];
#pragma unroll
        for (int t = 0; t < 4; t++) bfv[t] = *(const bf16x8*)&sPM[(j0 + t * 16 + fr) * 136 + 64 + kk + fq * 8];
#pragma unroll
        for (int i = 0; i < 4; i++)
#pragma unroll
            for (int j = 0; j < 4; j++)
                acc[i][j] = MFMA16(af[i], bfv[j], acc[i][j]);
    }

    float* Eb = E + ((size_t)(b * 128 + s)) * P_;
#pragma unroll
    for (int ti = 0; ti < 4; ti++)
#pragma unroll
        for (int r = 0; r < 4; r++) {
            const int i_g = i0 + ti * 16 + fq * 4 + r;
#pragma unroll
            for (int tj = 0; tj < 4; tj++) {
                const int j_g = j0 + tj * 16 + fr;
                float v = acc[ti][tj][r];
                if (mode && i_g == j_g) v = NEGV;
                Eb[(size_t)i_g * 128 + j_g] = v;
            }
        }
}

// ---------------------------------------------------------------------------
// Joint softmax over 128 row + 128 col logits per pixel; fp32 in, bf16 out.
__global__ __launch_bounds__(256) void ksoftmax(
    const float* __restrict__ ER, const float* __restrict__ EC,
    unsigned short* __restrict__ AR, unsigned short* __restrict__ AC)
{
    const int lane = threadIdx.x & 63;
    const int pix = blockIdx.x * 4 + (threadIdx.x >> 6);
    const int b = pix >> 14, rem = pix & 16383;
    const int h = rem >> 7, w = rem & 127;
    const size_t ro = ((size_t)((b * 128 + h) * 128 + w)) * 128;
    const size_t co = ((size_t)((b * 128 + w) * 128 + h)) * 128;
    const float2 r = *(const float2*)(ER + ro + lane * 2);
    const float2 c = *(const float2*)(EC + co + lane * 2);
    float mx = fmaxf(fmaxf(r.x, r.y), fmaxf(c.x, c.y));
#pragma unroll
    for (int off = 32; off > 0; off >>= 1) mx = fmaxf(mx, __shfl_xor(mx, off));
    const float e0 = __expf(r.x - mx), e1 = __expf(r.y - mx);
    const float e2 = __expf(c.x - mx), e3 = __expf(c.y - mx);
    float sm = e0 + e1 + e2 + e3;
#pragma unroll
    for (int off = 32; off > 0; off >>= 1) sm += __shfl_xor(sm, off);
    const float inv = 1.0f / sm;
    ushort2 u0; u0.x = f2bf(e0 * inv); u0.y = f2bf(e1 * inv);
    ushort2 u1; u1.x = f2bf(e2 * inv); u1.y = f2bf(e3 * inv);
    *(ushort2*)(AR + ro + lane * 2) = u0;
    *(ushort2*)(AC + co + lane * 2) = u1;
}

// ---------------------------------------------------------------------------
// Fused aggregation. Grid (s=128, b=4, mode=2), 256 threads.
// mode 0 (row): ySumR[b][p=s*128+i][c] = sum_j ARow[b][s][i][j] * x[b][c][s*128+j]
// mode 1 (col): ySumC[b][p=i*128+s][c] = sum_j ACol[b][s][i][j] * xTbf[b][c][s*128+j]
// Attention tile staged once via global_load_lds (swizzled source); X staged
// per 128-c tile (gl_lds for bf16 col mode, reg-convert for fp32 row mode).
// MFMA computes D[m=c][n=i] so each lane holds 4 consecutive c -> ushort4 stores.
__global__ __launch_bounds__(256) void kagg2(
    const unsigned short* __restrict__ ARow, const unsigned short* __restrict__ ACol,
    const float* __restrict__ x, const unsigned short* __restrict__ xTbf,
    unsigned short* __restrict__ ySumR, unsigned short* __restrict__ ySumC)
{
    __shared__ __attribute__((aligned(16))) unsigned short sAttn[128 * 128];
    __shared__ __attribute__((aligned(16))) unsigned short sX[128 * 128];
    const int tid = threadIdx.x;
    const int s = blockIdx.x, b = blockIdx.y, mode = blockIdx.z;
    const int lane = tid & 63, wv = tid >> 6;
    const int m0 = (wv >> 1) * 64, n0 = (wv & 1) * 64;   // m = c tile, n = i tile
    const int fr = lane & 15, fq = lane >> 4;

    // stage attention tile 128x128 once: linear LDS dest, inverse-swizzled src
    const unsigned short* At = (mode ? ACol : ARow) + ((size_t)(b * 128 + s)) * P_;
#pragma unroll
    for (int rep = 0; rep < 8; rep++) {
        const int idx = rep * 256 + tid;
        const int r = idx >> 4, sl = idx & 15;
        gl_lds16(&At[(size_t)r * 128 + (sl ^ (r & 7)) * 8], &sAttn[idx * 8]);
    }

    unsigned short* yS = mode ? ySumC : ySumR;

    for (int ct = 0; ct < 4; ct++) {
        if (mode == 0) {
            const float* Xf = &x[((size_t)(b * C_ + ct * 128)) * P_ + s * 128];
#pragma unroll
            for (int rep = 0; rep < 16; rep++) {
                const int idx = rep * 256 + tid;
                const int jq = idx & 31, cc = idx >> 5;
                const float4 v = *(const float4*)&Xf[(size_t)cc * P_ + jq * 4];
                ushort4 u; u.x = f2bf(v.x); u.y = f2bf(v.y); u.z = f2bf(v.z); u.w = f2bf(v.w);
                *(ushort4*)&sX[SWZ128(cc, jq * 4)] = u;
            }
        } else {
            const unsigned short* Xs = &xTbf[((size_t)(b * C_ + ct * 128)) * P_ + s * 128];
#pragma unroll
            for (int rep = 0; rep < 8; rep++) {
                const int idx = rep * 256 + tid;
                const int r = idx >> 4, sl = idx & 15;
                gl_lds16(&Xs[(size_t)r * P_ + (sl ^ (r & 7)) * 8], &sX[idx * 8]);
            }
        }
        __syncthreads();

        f32x4 acc[4][4];
#pragma unroll
        for (int i = 0; i < 4; i++)
#pragma unroll
            for (int j = 0; j < 4; j++) acc[i][j] = (f32x4){0.f, 0.f, 0.f, 0.f};

#pragma unroll
        for (int kk = 0; kk < 128; kk += 32) {
            bf16x8 af[4], bfv[4];
#pragma unroll
            for (int t = 0; t < 4; t++) {
                const int rc = m0 + t * 16 + fr;
                af[t] = *(const bf16x8*)&sX[SWZ128(rc, kk + fq * 8)];
            }
#pragma unroll
            for (int t = 0; t < 4; t++) {
                const int ri = n0 + t * 16 + fr;
                bfv[t] = *(const bf16x8*)&sAttn[SWZ128(ri, kk + fq * 8)];
            }
#pragma unroll
            for (int i = 0; i < 4; i++)
#pragma unroll
                for (int j = 0; j < 4; j++)
                    acc[i][j] = MFMA16(af[i], bfv[j], acc[i][j]);
        }

        // epilogue: lane holds c = cg0 + ti*16 + {0..3}, i = n0 + tj*16 + fr
        const int cg0 = ct * 128 + m0 + fq * 4;
#pragma unroll
        for (int tj = 0; tj < 4; tj++) {
            const int i_g = n0 + tj * 16 + fr;
            const size_t p = mode ? ((size_t)i_g * 128 + s) : ((size_t)s * 128 + i_g);
            unsigned short* rowp = yS + ((size_t)b * P_ + p) * 512;
#pragma unroll
            for (int ti = 0; ti < 4; ti++) {
                ushort4 u;
                u.x = f2bf(acc[ti][tj][0]); u.y = f2bf(acc[ti][tj][1]);
                u.z = f2bf(acc[ti][tj][2]); u.w = f2bf(acc[ti][tj][3]);
                *(ushort4*)&rowp[cg0 + ti * 16] = u;
            }
        }
        __syncthreads();   // all waves done reading sX before next ct overwrites it
    }
}

// ---------------------------------------------------------------------------
// Final GEMM as K=1024 concat: out[b][m][p] = gamma * sum_c Wv[m][c] *
// (yR[b][p][c] over chunks 0..7 | yC[b][p][c] over chunks 8..15) + x[b][m][p].
// Pure-DMA staging (global_load_lds w16, swizzled source), no combine VALU.
// Operands swapped (D rows = p) so epilogue is float4 loads/stores.
__global__ __launch_bounds__(256) void kfinal(
    const unsigned short* __restrict__ Wvbf,
    const unsigned short* __restrict__ yR,
    const unsigned short* __restrict__ yC,
    float* __restrict__ outf,
    const float* __restrict__ addx,
    const float* __restrict__ gammap)
{
    __shared__ __attribute__((aligned(16))) unsigned short sM[128 * 64]; // Wv rows
    __shared__ __attribute__((aligned(16))) unsigned short sP[128 * 64]; // ySum rows
    const int tid = threadIdx.x;
    const int pbase = blockIdx.x * 128, mt = blockIdx.y, b = blockIdx.z;
    const int lane = tid & 63, wv = tid >> 6;
    const int p0 = (wv >> 1) * 64, m0 = (wv & 1) * 64;
    const int fr = lane & 15, fq = lane >> 4;

    f32x4 acc[4][4];
#pragma unroll
    for (int i = 0; i < 4; i++)
#pragma unroll
        for (int j = 0; j < 4; j++) acc[i][j] = (f32x4){0.f, 0.f, 0.f, 0.f};

    const unsigned short* Arow = Wvbf + (size_t)(mt * 128) * 512;
    const size_t brow = ((size_t)b * P_ + pbase) * 512;

    for (int chunk = 0; chunk < 16; ++chunk) {
        const int kc = (chunk & 7) * 64;
        const unsigned short* Bp = (chunk < 8 ? yR : yC) + brow + kc;
        const unsigned short* Ap = Arow + kc;
        if (chunk) __syncthreads();      // prev chunk's ds_reads retired
#pragma unroll
        for (int rep = 0; rep < 4; rep++) {
            const int idx = rep * 256 + tid;
            const int r = idx >> 3, kgs = (idx & 7) ^ (r & 7);
            gl_lds16(&Ap[(size_t)r * 512 + kgs * 8], &sM[idx * 8]);
            gl_lds16(&Bp[(size_t)r * 512 + kgs * 8], &sP[idx * 8]);
        }
        __syncthreads();                 // drains vmcnt: tiles ready
#pragma unroll
        for (int kk = 0; kk < 64; kk += 32) {
            bf16x8 ap[4], am[4];
#pragma unroll
            for (int t = 0; t < 4; t++) {
                const int rp = p0 + t * 16 + fr;
                ap[t] = *(const bf16x8*)&sP[SWZ64(rp, kk + fq * 8)];
            }
#pragma unroll
            for (int t = 0; t < 4; t++) {
                const int rm = m0 + t * 16 + fr;
                am[t] = *(const bf16x8*)&sM[SWZ64(rm, kk + fq * 8)];
            }
#pragma unroll
            for (int i = 0; i < 4; i++)
#pragma unroll
                for (int j = 0; j < 4; j++)
                    acc[i][j] = MFMA16(ap[i], am[j], acc[i][j]);
        }
    }

    // epilogue: lane's 4 regs = 4 consecutive p; float4 RMW against addx
    const float g = gammap[0];
#pragma unroll
    for (int ti = 0; ti < 4; ti++) {
        const int p_g = pbase + p0 + ti * 16 + fq * 4;
#pragma unroll
        for (int tj = 0; tj < 4; tj++) {
            const int m_g = mt * 128 + m0 + tj * 16 + fr;
            const size_t off = ((size_t)(b * 512 + m_g)) * P_ + p_g;
            const float4 xa = *(const float4*)&addx[off];
            float4 o;
            o.x = fmaf(g, acc[ti][tj][0], xa.x);
            o.y = fmaf(g, acc[ti][tj][1], xa.y);
            o.z = fmaf(g, acc[ti][tj][2], xa.z);
            o.w = fmaf(g, acc[ti][tj][3], xa.w);
            *(float4*)&outf[off] = o;
        }
    }
}

// ---------------------------------------------------------------------------
extern "C" void kernel_launch(void* const* d_in, const int* in_sizes, int n_in,
                              void* d_out, int out_size, void* d_ws, size_t ws_size,
                              hipStream_t stream) {
    const float* x     = (const float*)d_in[0];
    const float* Wq    = (const float*)d_in[1];
    const float* Wk    = (const float*)d_in[2];
    const float* Wv    = (const float*)d_in[3];
    const float* gamma = (const float*)d_in[4];
    float* out = (float*)d_out;

    char* base = (char*)d_ws;
    unsigned short* Wqkbf = (unsigned short*)base;             base += 131072;      // 128x512
    unsigned short* Wvbf  = (unsigned short*)base;             base += 524288;      // 512x512
    unsigned short* xTbf  = (unsigned short*)base;             base += 67108864;    // [b][c][w][h]
    unsigned short* xbfT  = (unsigned short*)base;             base += 67108864;    // [b][p][c]
    unsigned short* qkP   = (unsigned short*)base;             base += 16777216;    // [b][p][mk]
    float*          ERow  = (float*)base;                      base += 33554432;    // [b][h][i][j]
    float*          ECol  = (float*)base;                      base += 33554432;    // [b][w][i][j]
    unsigned short* ARow  = (unsigned short*)base;             base += 16777216;
    unsigned short* ACol  = (unsigned short*)base;             base += 16777216;
    unsigned short* ySumR = (unsigned short*)base;             base += 67108864;    // [b][p][c]
    // ySumC aliases the dead ERow+ECol region (exactly 64 MiB, free after ksoftmax)
    unsigned short* ySumC = (unsigned short*)ERow;

    kwconv<<<320, 256, 0, stream>>>(Wq, Wk, Wv, Wqkbf, Wvbf);
    kprep1<<<dim3(16, 2048), dim3(32, 8), 0, stream>>>(x, xTbf);
    kprep2<<<dim3(512, 16, 4), dim3(32, 8), 0, stream>>>(x, xbfT);
    // qk[b][p][mk] = Wqk @ x
    kgemmqk<<<dim3(128, 1, 4), 256, 0, stream>>>(Wqkbf, xbfT, qkP);
    // row (eW) + col (eH, diag-masked) logits in one launch
    klogits<<<dim3(128, 4, 2), 256, 0, stream>>>(qkP, ERow, ECol);
    ksoftmax<<<16384, 256, 0, stream>>>(ERow, ECol, ARow, ACol);
    // fused row+col aggregation -> ySumR / ySumC (no RMW)
    kagg2<<<dim3(128, 4, 2), 256, 0, stream>>>(ARow, ACol, x, xTbf, ySumR, ySumC);
    // out = gamma * Wv @ [ySumR | ySumC] (K=1024 concat) + x
    kfinal<<<dim3(128, 4, 4), 256, 0, stream>>>(Wvbf, ySumR, ySumC, out, x, gamma);
}

// Round 3
// 515.571 us; speedup vs baseline: 1.0830x; 1.0426x over previous
//
#include <hip/hip_runtime.h>
#include <cstdint>
#include <cstddef>

#define NEGV (-1e30f)

constexpr int C_ = 512, H_ = 128, W_ = 128;
constexpr int P_ = 16384;   // H*W

typedef short bf16x8 __attribute__((ext_vector_type(8)));
typedef float f32x4  __attribute__((ext_vector_type(4)));
typedef _Float16 f16x4 __attribute__((ext_vector_type(4)));
#define MFMA16(a, b, c) __builtin_amdgcn_mfma_f32_16x16x32_bf16((a), (b), (c), 0, 0, 0)

// Swizzled LDS offsets (units: shorts). 16B slots XOR'd with row&7 so that
// stride-128B/256B column reads (ds_read_b128) spread across all banks.
// Rule #21: with global_load_lds the LDS dest is LINEAR (idx*16B) and the
// GLOBAL source slot is pre-XOR'd with the same involution; reads use SWZ*.
#define SWZ128(r, cs) (((r) << 7) + (((((cs) >> 3) ^ ((r) & 7))) << 3) + ((cs) & 7))
#define SWZ64(r, cs)  (((r) << 6) + (((((cs) >> 3) ^ ((r) & 7))) << 3) + ((cs) & 7))

__device__ inline void gl_lds16(const void* g, void* l) {
    __builtin_amdgcn_global_load_lds(
        (const __attribute__((address_space(1))) unsigned int*)g,
        (__attribute__((address_space(3))) unsigned int*)l, 16, 0, 0);
}

__device__ inline unsigned short f2bf(float f) {
    union { float f; uint32_t i; } t; t.f = f;
    uint32_t r = t.i + 0x7FFFu + ((t.i >> 16) & 1u);   // RNE
    return (unsigned short)(r >> 16);
}

// ---------------------------------------------------------------------------
// Weight conversion: Wq,Wk -> Wqkbf[128][512] (q rows 0..63, k rows 64..127);
// Wv -> Wvbf[512][512]. 4 elems/thread.
__global__ __launch_bounds__(256) void kwconv(
    const float* __restrict__ Wq, const float* __restrict__ Wk,
    const float* __restrict__ Wv,
    unsigned short* __restrict__ Wqkbf, unsigned short* __restrict__ Wvbf)
{
    const int i4 = (blockIdx.x * 256 + threadIdx.x) * 4;
    const float* src; unsigned short* dst; int off;
    if (i4 < 32768)       { src = Wq + i4;          dst = Wqkbf + i4; }
    else if (i4 < 65536)  { off = i4 - 32768; src = Wk + off; dst = Wqkbf + i4; }
    else                  { off = i4 - 65536; src = Wv + off; dst = Wvbf + off; }
    const float4 v = *(const float4*)src;
    ushort4 u; u.x = f2bf(v.x); u.y = f2bf(v.y); u.z = f2bf(v.z); u.w = f2bf(v.w);
    *(ushort4*)dst = u;
}

// ---------------------------------------------------------------------------
// x[b][c][h][w] fp32 -> xTbf[b][c][w][h] bf16 (per-map 128x128 transpose)
// 32x32 tiles, float4 in / ushort4 out.
__global__ __launch_bounds__(256) void kprep1(
    const float* __restrict__ x, unsigned short* __restrict__ xTbf)
{
    __shared__ float t[32][33];
    const int tid = threadIdx.x;
    const int h0 = (blockIdx.x >> 2) * 32, w0 = (blockIdx.x & 3) * 32;
    const size_t base = (size_t)blockIdx.y * P_;
    {
        const int r = tid >> 3, c4 = (tid & 7) * 4;
        const float4 v = *(const float4*)&x[base + (size_t)(h0 + r) * 128 + w0 + c4];
        t[r][c4] = v.x; t[r][c4 + 1] = v.y; t[r][c4 + 2] = v.z; t[r][c4 + 3] = v.w;
    }
    __syncthreads();
    {
        const int wr = tid >> 3, hc = (tid & 7) * 4;
        ushort4 u;
        u.x = f2bf(t[hc][wr]);     u.y = f2bf(t[hc + 1][wr]);
        u.z = f2bf(t[hc + 2][wr]); u.w = f2bf(t[hc + 3][wr]);
        *(ushort4*)&xTbf[base + (size_t)(w0 + wr) * 128 + h0 + hc] = u;
    }
}

// x[b][c][p] fp32 -> xbfT[b][p][c] bf16  (c <-> p transpose), tiles 32c x 32p
__global__ __launch_bounds__(256) void kprep2(
    const float* __restrict__ x, unsigned short* __restrict__ xbfT)
{
    __shared__ float t[32][33];
    const int tid = threadIdx.x;
    const int p0 = blockIdx.x * 32, c0 = blockIdx.y * 32, b = blockIdx.z;
    {
        const int r = tid >> 3, c4 = (tid & 7) * 4;     // r = c index, c4 = p index
        const float4 v = *(const float4*)&x[((size_t)(b * C_ + c0 + r)) * P_ + p0 + c4];
        t[r][c4] = v.x; t[r][c4 + 1] = v.y; t[r][c4 + 2] = v.z; t[r][c4 + 3] = v.w;
    }
    __syncthreads();
    {
        const int pr = tid >> 3, cc = (tid & 7) * 4;
        ushort4 u;
        u.x = f2bf(t[cc][pr]);     u.y = f2bf(t[cc + 1][pr]);
        u.z = f2bf(t[cc + 2][pr]); u.w = f2bf(t[cc + 3][pr]);
        *(ushort4*)&xbfT[((size_t)b * P_ + p0 + pr) * C_ + c0 + cc] = u;
    }
}

// ---------------------------------------------------------------------------
// QK projection GEMM, K=512, 2-deep pipelined (counted vmcnt, raw s_barrier).
// D[m][n=p] = sum_c A[m][c] * Bm[p][c]; A = Wqkbf [128][512]; Bm = xbfT.
// Store bf16 at qkP[b][p][mk].
__global__ __launch_bounds__(256) void kgemmqk(
    const unsigned short* __restrict__ A, const unsigned short* __restrict__ Bm,
    unsigned short* __restrict__ outbf)
{
    __shared__ __attribute__((aligned(16))) unsigned short sA[2][128 * 64];
    __shared__ __attribute__((aligned(16))) unsigned short sB[2][128 * 64];
    const int tid = threadIdx.x;
    const int pbase = blockIdx.x * 128, b = blockIdx.z;
    const int lane = tid & 63, wv = tid >> 6;
    const int m0 = (wv >> 1) * 64, p0 = (wv & 1) * 64;
    const int fr = lane & 15, fq = lane >> 4;

    f32x4 acc[4][4];
#pragma unroll
    for (int i = 0; i < 4; i++)
#pragma unroll
        for (int j = 0; j < 4; j++) acc[i][j] = (f32x4){0.f, 0.f, 0.f, 0.f};

    const size_t brow0 = ((size_t)b * P_ + pbase) * 512;

#define QK_STAGE(chunk, buf) {                                                  \
        const int kc_ = (chunk) * 64;                                           \
        _Pragma("unroll")                                                       \
        for (int rep = 0; rep < 4; rep++) {                                     \
            const int idx = rep * 256 + tid;                                    \
            const int r_ = idx >> 3, kgs = (idx & 7) ^ (r_ & 7);                \
            gl_lds16(&A[(size_t)r_ * 512 + kc_ + kgs * 8], &sA[buf][idx * 8]);  \
            gl_lds16(&Bm[brow0 + (size_t)r_ * 512 + kc_ + kgs * 8], &sB[buf][idx * 8]); \
        } }

    QK_STAGE(0, 0);
    int cur = 0;
    for (int chunk = 0; chunk < 8; ++chunk) {
        if (chunk < 7) {
            QK_STAGE(chunk + 1, cur ^ 1);
            asm volatile("s_waitcnt vmcnt(8)" ::: "memory");   // chunk's 8 landed
        } else {
            asm volatile("s_waitcnt vmcnt(0)" ::: "memory");
        }
        __builtin_amdgcn_s_barrier();
#pragma unroll
        for (int kk = 0; kk < 64; kk += 32) {
            bf16x8 af[4], bfv[4];
#pragma unroll
            for (int t = 0; t < 4; t++) af[t]  = *(const bf16x8*)&sA[cur][SWZ64(m0 + t * 16 + fr, kk + fq * 8)];
#pragma unroll
            for (int t = 0; t < 4; t++) bfv[t] = *(const bf16x8*)&sB[cur][SWZ64(p0 + t * 16 + fr, kk + fq * 8)];
#pragma unroll
            for (int i = 0; i < 4; i++)
#pragma unroll
                for (int j = 0; j < 4; j++)
                    acc[i][j] = MFMA16(af[i], bfv[j], acc[i][j]);
        }
        if (chunk < 7) __builtin_amdgcn_s_barrier();   // readers done before re-stage
        cur ^= 1;
    }
#undef QK_STAGE

    // qkP[b][p][mk] bf16, pack 4 consecutive mk (quad*4+r) per store
#pragma unroll
    for (int tj = 0; tj < 4; tj++) {
        const int p_g = pbase + p0 + tj * 16 + fr;
        const size_t rowo = ((size_t)b * P_ + p_g) * 128;
#pragma unroll
        for (int ti = 0; ti < 4; ti++) {
            const int mk = m0 + ti * 16 + fq * 4;
            ushort4 u;
            u.x = f2bf(acc[ti][tj][0]); u.y = f2bf(acc[ti][tj][1]);
            u.z = f2bf(acc[ti][tj][2]); u.w = f2bf(acc[ti][tj][3]);
            *(ushort4*)&outbf[rowo + mk] = u;
        }
    }
}

// ---------------------------------------------------------------------------
// Logits, fused row/col via blockIdx.z, fp16 output:
// per (b, s): E[i][j] = sum_{m<64} Q[m][i]*K[m][j], Q/K from qkP[b][p][mk]
// mode 0 (row, -> ERow): p(i) = s*128 + i
// mode 1 (col, -> ECol): p(i) = i*128 + s, diag mask
__global__ __launch_bounds__(256) void klogits(
    const unsigned short* __restrict__ qkP,
    _Float16* __restrict__ ERow, _Float16* __restrict__ ECol)
{
    __shared__ __attribute__((aligned(16))) unsigned short sPM[128 * 136];
    const int tid = threadIdx.x;
    const int s = blockIdx.x, b = blockIdx.y, mode = blockIdx.z;
    const int rowMul  = mode ? 1 : 128;
    const int rowStep = mode ? 128 : 1;
    _Float16* E = mode ? ECol : ERow;
    const size_t qbase = (size_t)b * P_ * 128;
    const int rb = s * rowMul;
#pragma unroll
    for (int rep = 0; rep < 8; rep++) {
        const int idx = rep * 256 + tid;
        const int mkg = idx & 15, i = idx >> 4;
        *(uint4*)&sPM[i * 136 + mkg * 8] =
            *(const uint4*)&qkP[qbase + (size_t)(rb + i * rowStep) * 128 + mkg * 8];
    }
    __syncthreads();

    const int lane = tid & 63, wv = tid >> 6;
    const int i0 = (wv >> 1) * 64, j0 = (wv & 1) * 64;
    const int fr = lane & 15, fq = lane >> 4;

    f32x4 acc[4][4];
#pragma unroll
    for (int i = 0; i < 4; i++)
#pragma unroll
        for (int j = 0; j < 4; j++) acc[i][j] = (f32x4){0.f, 0.f, 0.f, 0.f};

#pragma unroll
    for (int kk = 0; kk < 64; kk += 32) {
        bf16x8 af[4], bfv[4];
#pragma unroll
        for (int t = 0; t < 4; t++) af[t]  = *(const bf16x8*)&sPM[(i0 + t * 16 + fr) * 136 + kk + fq * 8];
#pragma unroll
        for (int t = 0; t < 4; t++) bfv[t] = *(const bf16x8*)&sPM[(j0 + t * 16 + fr) * 136 + 64 + kk + fq * 8];
#pragma unroll
        for (int i = 0; i < 4; i++)
#pragma unroll
            for (int j = 0; j < 4; j++)
                acc[i][j] = MFMA16(af[i], bfv[j], acc[i][j]);
    }

    _Float16* Eb = E + ((size_t)(b * 128 + s)) * P_;
#pragma unroll
    for (int ti = 0; ti < 4; ti++)
#pragma unroll
        for (int r = 0; r < 4; r++) {
            const int i_g = i0 + ti * 16 + fq * 4 + r;
#pragma unroll
            for (int tj = 0; tj < 4; tj++) {
                const int j_g = j0 + tj * 16 + fr;
                float v = acc[ti][tj][r];
                if (mode && i_g == j_g) v = -60000.0f;   // fp16-representable NEG
                Eb[(size_t)i_g * 128 + j_g] = (_Float16)v;
            }
        }
}

// ---------------------------------------------------------------------------
// Joint softmax over 128 row + 128 col fp16 logits per pixel; bf16 out.
// 32 lanes per pixel, 8 B/lane loads, 8 pixels/block.
__global__ __launch_bounds__(256) void ksoftmax(
    const _Float16* __restrict__ ER, const _Float16* __restrict__ EC,
    unsigned short* __restrict__ AR, unsigned short* __restrict__ AC)
{
    const int tid = threadIdx.x;
    const int l32 = tid & 31;
    const int pix = blockIdx.x * 8 + (tid >> 5);
    const int b = pix >> 14, rem = pix & 16383;
    const int h = rem >> 7, w = rem & 127;
    const size_t ro = ((size_t)((b * 128 + h) * 128 + w)) * 128;
    const size_t co = ((size_t)((b * 128 + w) * 128 + h)) * 128;
    const f16x4 r = *(const f16x4*)(ER + ro + l32 * 4);
    const f16x4 c = *(const f16x4*)(EC + co + l32 * 4);
    const float r0 = r.x, r1 = r.y, r2 = r.z, r3 = r.w;
    const float c0 = c.x, c1 = c.y, c2 = c.z, c3 = c.w;
    float mx = fmaxf(fmaxf(fmaxf(r0, r1), fmaxf(r2, r3)),
                     fmaxf(fmaxf(c0, c1), fmaxf(c2, c3)));
#pragma unroll
    for (int off = 16; off > 0; off >>= 1) mx = fmaxf(mx, __shfl_xor(mx, off));
    const float e0 = __expf(r0 - mx), e1 = __expf(r1 - mx);
    const float e2 = __expf(r2 - mx), e3 = __expf(r3 - mx);
    const float f0 = __expf(c0 - mx), f1 = __expf(c1 - mx);
    const float f2 = __expf(c2 - mx), f3 = __expf(c3 - mx);
    float sm = (e0 + e1 + e2 + e3) + (f0 + f1 + f2 + f3);
#pragma unroll
    for (int off = 16; off > 0; off >>= 1) sm += __shfl_xor(sm, off);
    const float inv = 1.0f / sm;
    ushort4 u0, u1;
    u0.x = f2bf(e0 * inv); u0.y = f2bf(e1 * inv); u0.z = f2bf(e2 * inv); u0.w = f2bf(e3 * inv);
    u1.x = f2bf(f0 * inv); u1.y = f2bf(f1 * inv); u1.z = f2bf(f2 * inv); u1.w = f2bf(f3 * inv);
    *(ushort4*)(AR + ro + l32 * 4) = u0;
    *(ushort4*)(AC + co + l32 * 4) = u1;
}

// ---------------------------------------------------------------------------
// Fused aggregation. Grid (s=128, b=4, mode=2), 256 threads.
// mode 0 (row): ySumR[b][p=s*128+i][c] = sum_j ARow[b][s][i][j] * x[b][c][s*128+j]
// mode 1 (col): ySumC[b][p=i*128+s][c] = sum_j ACol[b][s][i][j] * xTbf[b][c][s*128+j]
__global__ __launch_bounds__(256) void kagg2(
    const unsigned short* __restrict__ ARow, const unsigned short* __restrict__ ACol,
    const float* __restrict__ x, const unsigned short* __restrict__ xTbf,
    unsigned short* __restrict__ ySumR, unsigned short* __restrict__ ySumC)
{
    __shared__ __attribute__((aligned(16))) unsigned short sAttn[128 * 128];
    __shared__ __attribute__((aligned(16))) unsigned short sX[128 * 128];
    const int tid = threadIdx.x;
    const int s = blockIdx.x, b = blockIdx.y, mode = blockIdx.z;
    const int lane = tid & 63, wv = tid >> 6;
    const int m0 = (wv >> 1) * 64, n0 = (wv & 1) * 64;   // m = c tile, n = i tile
    const int fr = lane & 15, fq = lane >> 4;

    // stage attention tile 128x128 once: linear LDS dest, inverse-swizzled src
    const unsigned short* At = (mode ? ACol : ARow) + ((size_t)(b * 128 + s)) * P_;
#pragma unroll
    for (int rep = 0; rep < 8; rep++) {
        const int idx = rep * 256 + tid;
        const int r = idx >> 4, sl = idx & 15;
        gl_lds16(&At[(size_t)r * 128 + (sl ^ (r & 7)) * 8], &sAttn[idx * 8]);
    }

    unsigned short* yS = mode ? ySumC : ySumR;

    for (int ct = 0; ct < 4; ct++) {
        if (mode == 0) {
            const float* Xf = &x[((size_t)(b * C_ + ct * 128)) * P_ + s * 128];
#pragma unroll
            for (int rep = 0; rep < 16; rep++) {
                const int idx = rep * 256 + tid;
                const int jq = idx & 31, cc = idx >> 5;
                const float4 v = *(const float4*)&Xf[(size_t)cc * P_ + jq * 4];
                ushort4 u; u.x = f2bf(v.x); u.y = f2bf(v.y); u.z = f2bf(v.z); u.w = f2bf(v.w);
                *(ushort4*)&sX[SWZ128(cc, jq * 4)] = u;
            }
        } else {
            const unsigned short* Xs = &xTbf[((size_t)(b * C_ + ct * 128)) * P_ + s * 128];
#pragma unroll
            for (int rep = 0; rep < 8; rep++) {
                const int idx = rep * 256 + tid;
                const int r = idx >> 4, sl = idx & 15;
                gl_lds16(&Xs[(size_t)r * P_ + (sl ^ (r & 7)) * 8], &sX[idx * 8]);
            }
        }
        __syncthreads();

        f32x4 acc[4][4];
#pragma unroll
        for (int i = 0; i < 4; i++)
#pragma unroll
            for (int j = 0; j < 4; j++) acc[i][j] = (f32x4){0.f, 0.f, 0.f, 0.f};

#pragma unroll
        for (int kk = 0; kk < 128; kk += 32) {
            bf16x8 af[4], bfv[4];
#pragma unroll
            for (int t = 0; t < 4; t++) {
                const int rc = m0 + t * 16 + fr;
                af[t] = *(const bf16x8*)&sX[SWZ128(rc, kk + fq * 8)];
            }
#pragma unroll
            for (int t = 0; t < 4; t++) {
                const int ri = n0 + t * 16 + fr;
                bfv[t] = *(const bf16x8*)&sAttn[SWZ128(ri, kk + fq * 8)];
            }
#pragma unroll
            for (int i = 0; i < 4; i++)
#pragma unroll
                for (int j = 0; j < 4; j++)
                    acc[i][j] = MFMA16(af[i], bfv[j], acc[i][j]);
        }

        // epilogue: lane holds c = cg0 + ti*16 + {0..3}, i = n0 + tj*16 + fr
        const int cg0 = ct * 128 + m0 + fq * 4;
#pragma unroll
        for (int tj = 0; tj < 4; tj++) {
            const int i_g = n0 + tj * 16 + fr;
            const size_t p = mode ? ((size_t)i_g * 128 + s) : ((size_t)s * 128 + i_g);
            unsigned short* rowp = yS + ((size_t)b * P_ + p) * 512;
#pragma unroll
            for (int ti = 0; ti < 4; ti++) {
                ushort4 u;
                u.x = f2bf(acc[ti][tj][0]); u.y = f2bf(acc[ti][tj][1]);
                u.z = f2bf(acc[ti][tj][2]); u.w = f2bf(acc[ti][tj][3]);
                *(ushort4*)&rowp[cg0 + ti * 16] = u;
            }
        }
        __syncthreads();   // all waves done reading sX before next ct overwrites it
    }
}

// ---------------------------------------------------------------------------
// Final GEMM as K=1024 concat, 2-deep pipelined (counted vmcnt, raw s_barrier):
// out[b][m][p] = gamma * sum_c Wv[m][c] * (yR|yC)[b][p][c] + x[b][m][p].
// Operands swapped (D rows = p) so epilogue is float4 loads/stores.
__global__ __launch_bounds__(256) void kfinal(
    const unsigned short* __restrict__ Wvbf,
    const unsigned short* __restrict__ yR,
    const unsigned short* __restrict__ yC,
    float* __restrict__ outf,
    const float* __restrict__ addx,
    const float* __restrict__ gammap)
{
    __shared__ __attribute__((aligned(16))) unsigned short sM[2][128 * 64]; // Wv rows
    __shared__ __attribute__((aligned(16))) unsigned short sP[2][128 * 64]; // ySum rows
    const int tid = threadIdx.x;
    const int pbase = blockIdx.x * 128, mt = blockIdx.y, b = blockIdx.z;
    const int lane = tid & 63, wv = tid >> 6;
    const int p0 = (wv >> 1) * 64, m0 = (wv & 1) * 64;
    const int fr = lane & 15, fq = lane >> 4;

    f32x4 acc[4][4];
#pragma unroll
    for (int i = 0; i < 4; i++)
#pragma unroll
        for (int j = 0; j < 4; j++) acc[i][j] = (f32x4){0.f, 0.f, 0.f, 0.f};

    const unsigned short* Arow = Wvbf + (size_t)(mt * 128) * 512;
    const size_t brow = ((size_t)b * P_ + pbase) * 512;

#define FIN_STAGE(chunk, buf) {                                                 \
        const int kc_ = ((chunk) & 7) * 64;                                     \
        const unsigned short* Bp = ((chunk) < 8 ? yR : yC) + brow + kc_;        \
        const unsigned short* Ap = Arow + kc_;                                  \
        _Pragma("unroll")                                                       \
        for (int rep = 0; rep < 4; rep++) {                                     \
            const int idx = rep * 256 + tid;                                    \
            const int r_ = idx >> 3, kgs = (idx & 7) ^ (r_ & 7);                \
            gl_lds16(&Ap[(size_t)r_ * 512 + kgs * 8], &sM[buf][idx * 8]);       \
            gl_lds16(&Bp[(size_t)r_ * 512 + kgs * 8], &sP[buf][idx * 8]);       \
        } }

    FIN_STAGE(0, 0);
    int cur = 0;
    for (int chunk = 0; chunk < 16; ++chunk) {
        if (chunk < 15) {
            FIN_STAGE(chunk + 1, cur ^ 1);
            asm volatile("s_waitcnt vmcnt(8)" ::: "memory");   // chunk's 8 landed
        } else {
            asm volatile("s_waitcnt vmcnt(0)" ::: "memory");
        }
        __builtin_amdgcn_s_barrier();
#pragma unroll
        for (int kk = 0; kk < 64; kk += 32) {
            bf16x8 ap[4], am[4];
#pragma unroll
            for (int t = 0; t < 4; t++) ap[t] = *(const bf16x8*)&sP[cur][SWZ64(p0 + t * 16 + fr, kk + fq * 8)];
#pragma unroll
            for (int t = 0; t < 4; t++) am[t] = *(const bf16x8*)&sM[cur][SWZ64(m0 + t * 16 + fr, kk + fq * 8)];
#pragma unroll
            for (int i = 0; i < 4; i++)
#pragma unroll
                for (int j = 0; j < 4; j++)
                    acc[i][j] = MFMA16(ap[i], am[j], acc[i][j]);
        }
        if (chunk < 15) __builtin_amdgcn_s_barrier();  // readers done before re-stage
        cur ^= 1;
    }
#undef FIN_STAGE

    // epilogue: lane's 4 regs = 4 consecutive p; float4 RMW against addx
    const float g = gammap[0];
#pragma unroll
    for (int ti = 0; ti < 4; ti++) {
        const int p_g = pbase + p0 + ti * 16 + fq * 4;
#pragma unroll
        for (int tj = 0; tj < 4; tj++) {
            const int m_g = mt * 128 + m0 + tj * 16 + fr;
            const size_t off = ((size_t)(b * 512 + m_g)) * P_ + p_g;
            const float4 xa = *(const float4*)&addx[off];
            float4 o;
            o.x = fmaf(g, acc[ti][tj][0], xa.x);
            o.y = fmaf(g, acc[ti][tj][1], xa.y);
            o.z = fmaf(g, acc[ti][tj][2], xa.z);
            o.w = fmaf(g, acc[ti][tj][3], xa.w);
            *(float4*)&outf[off] = o;
        }
    }
}

// ---------------------------------------------------------------------------
extern "C" void kernel_launch(void* const* d_in, const int* in_sizes, int n_in,
                              void* d_out, int out_size, void* d_ws, size_t ws_size,
                              hipStream_t stream) {
    const float* x     = (const float*)d_in[0];
    const float* Wq    = (const float*)d_in[1];
    const float* Wk    = (const float*)d_in[2];
    const float* Wv    = (const float*)d_in[3];
    const float* gamma = (const float*)d_in[4];
    float* out = (float*)d_out;

    char* base = (char*)d_ws;
    unsigned short* Wqkbf = (unsigned short*)base;             base += 131072;      // 128x512
    unsigned short* Wvbf  = (unsigned short*)base;             base += 524288;      // 512x512
    unsigned short* xTbf  = (unsigned short*)base;             base += 67108864;    // [b][c][w][h]
    unsigned short* xbfT  = (unsigned short*)base;             base += 67108864;    // [b][p][c]
    unsigned short* qkP   = (unsigned short*)base;             base += 16777216;    // [b][p][mk]
    _Float16*       ERow  = (_Float16*)base;                   base += 33554432;    // [b][h][i][j] fp16 (half-used)
    _Float16*       ECol  = (_Float16*)base;                   base += 33554432;    // [b][w][i][j] fp16 (half-used)
    unsigned short* ARow  = (unsigned short*)base;             base += 16777216;
    unsigned short* ACol  = (unsigned short*)base;             base += 16777216;
    unsigned short* ySumR = (unsigned short*)base;             base += 67108864;    // [b][p][c]
    // ySumC aliases the dead ERow+ECol region (64 MiB combined, free after ksoftmax)
    unsigned short* ySumC = (unsigned short*)ERow;

    kwconv<<<320, 256, 0, stream>>>(Wq, Wk, Wv, Wqkbf, Wvbf);
    kprep1<<<dim3(16, 2048), 256, 0, stream>>>(x, xTbf);
    kprep2<<<dim3(512, 16, 4), 256, 0, stream>>>(x, xbfT);
    // qk[b][p][mk] = Wqk @ x
    kgemmqk<<<dim3(128, 1, 4), 256, 0, stream>>>(Wqkbf, xbfT, qkP);
    // row (eW) + col (eH, diag-masked) logits in one launch, fp16 out
    klogits<<<dim3(128, 4, 2), 256, 0, stream>>>(qkP, ERow, ECol);
    ksoftmax<<<8192, 256, 0, stream>>>(ERow, ECol, ARow, ACol);
    // fused row+col aggregation -> ySumR / ySumC (no RMW)
    kagg2<<<dim3(128, 4, 2), 256, 0, stream>>>(ARow, ACol, x, xTbf, ySumR, ySumC);
    // out = gamma * Wv @ [ySumR | ySumC] (K=1024 concat) + x
    kfinal<<<dim3(128, 4, 4), 256, 0, stream>>>(Wvbf, ySumR, ySumC, out, x, gamma);
}